// Round 10
// baseline (101.156 us; speedup 1.0000x reference)
//
#include <hip/hip_runtime.h>
#include <math.h>

#define NB 4      // batch
#define NP 144    // output spatial positions (12x12)
#define KW 9      // kernel window (3x3)
#define CIN 32
#define NC 32     // output capsules
#define NK 288    // KW*CIN children
#define ND 16     // pose dims
#define NDH 8     // ND/2 (packed float2)
#define EPSI 1e-7f
#define NT 512
#define KPT 18        // k per thread
#define NRED 4        // reduction groups (waves 4-7 write, 0-3 add)

// One block per (b,p). c = t&31, s = t>>5 (k-slice), 18 k per thread.
// KEY CHANGE r10: #pragma unroll 1 on the big k-loops and the it-loop.
// Theory: -O3 fully unrolled the 9-trip jj-loops (~250 instr bodies) ->
// ~40-50KB hot code > 32KB I-cache -> all waves stream instructions from L2.
// Explains the ~110us floor insensitive to VALU count (r9 packing: -2%),
// DS-op count (r5 DPP: -0%), occupancy (r2: -0%), W-prefetch (r8: -8%),
// while every pipe counter reads idle and total VALU work is only ~22us.
// Inner d-loops stay fully unrolled (register arrays need static indices).
// Keeps r8/r9: W reg-prefetch ping-pong, packed float2 math, DPP softmax,
// exp2 domain, 41KB LDS. launch_bounds single-arg ONLY (r3/r4 spills).

typedef float v2f __attribute__((ext_vector_type(2)));

__device__ __forceinline__ v2f mkv2(float a, float b) { v2f r; r[0] = a; r[1] = b; return r; }

template<int CTRL>
__device__ __forceinline__ float dppf(float x) {
    return __int_as_float(__builtin_amdgcn_update_dpp(
        0, __float_as_int(x), CTRL, 0xF, 0xF, true));
}
// 0xB1=quad_perm xor1 ; 0x4E=quad_perm xor2 ; 0x141=row_half_mirror (xor4 once
// 4-uniform) ; 0x140=row_mirror (xor8 once 8-uniform)
__device__ __forceinline__ float swz16(float x) {
    return __int_as_float(__builtin_amdgcn_ds_swizzle(__float_as_int(x), 0x401F));
}
__device__ __forceinline__ float red32_max(float x) {
    x = fmaxf(x, dppf<0xB1>(x));
    x = fmaxf(x, dppf<0x4E>(x));
    x = fmaxf(x, dppf<0x141>(x));
    x = fmaxf(x, dppf<0x140>(x));
    x = fmaxf(x, swz16(x));
    return x;
}
__device__ __forceinline__ float red32_sum(float x) {
    x += dppf<0xB1>(x);
    x += dppf<0x4E>(x);
    x += dppf<0x141>(x);
    x += dppf<0x140>(x);
    x += swz16(x);
    return x;
}
__device__ __forceinline__ float red16_sum(float x) {  // sum over lane bits 0-3
    x += dppf<0xB1>(x);
    x += dppf<0x4E>(x);
    x += dppf<0x141>(x);
    x += dppf<0x140>(x);
    return x;
}

__device__ __forceinline__ int sw4(int c, int j) { return j ^ ((c >> 1) & 3); }

__device__ __forceinline__ void load16(const float* src, float* dst) {
    const float4* s4 = (const float4*)src;
    *(float4*)&dst[0]  = s4[0];
    *(float4*)&dst[4]  = s4[1];
    *(float4*)&dst[8]  = s4[2];
    *(float4*)&dst[12] = s4[3];
}
// 16B loads, repacked into 8 float2 register pairs
__device__ __forceinline__ void load16v(const float* src, v2f* dst) {
    const float4* s4 = (const float4*)src;
    #pragma unroll
    for (int q = 0; q < 4; ++q) {
        const float4 tq = s4[q];
        dst[q*2+0] = mkv2(tq.x, tq.y);
        dst[q*2+1] = mkv2(tq.z, tq.w);
    }
}

// vote pairs over l: v2[i*2+p] = {vote[i*4+2p], vote[i*4+2p+1]} == d-pair 2e,2e+1
__device__ __forceinline__ void vote44v(const float* pr, const v2f* wr2, v2f* v2) {
    #pragma unroll
    for (int i = 0; i < 4; ++i) {
        const v2f p0 = mkv2(pr[i*4+0], pr[i*4+0]);
        const v2f p1 = mkv2(pr[i*4+1], pr[i*4+1]);
        const v2f p2 = mkv2(pr[i*4+2], pr[i*4+2]);
        const v2f p3 = mkv2(pr[i*4+3], pr[i*4+3]);
        #pragma unroll
        for (int p = 0; p < 2; ++p) {
            v2f acc = p0 * wr2[0*2+p];
            acc += p1 * wr2[1*2+p];
            acc += p2 * wr2[2*2+p];
            acc += p3 * wr2[3*2+p];
            v2[i*2+p] = acc;
        }
    }
}

// E-step + M-accumulate for one (k, c), packed
__device__ __forceinline__ void estep_body(
    const v2f v2[NDH], float actk,
    const v2f iv2v[NDH], const v2f h2n2v[NDH], float A2,
    float& r0, v2f m1v[NDH], v2f m2v[NDH])
{
    v2f q2v = mkv2(0.0f, 0.0f);
    #pragma unroll
    for (int e = 0; e < NDH; ++e)
        q2v += (iv2v[e] * v2[e] + h2n2v[e]) * v2[e];
    const float logit2 = A2 - (q2v[0] + q2v[1]);

    const float mx = red32_max(logit2);
    const float e  = __builtin_amdgcn_exp2f(logit2 - mx);
    const float se = red32_sum(e);
    const float rp = e * __builtin_amdgcn_rcpf(se) * actk;
    r0 += rp;
    const v2f rpv = mkv2(rp, rp);
    #pragma unroll
    for (int d = 0; d < NDH; ++d) {
        const v2f rv = rpv * v2[d];
        m1v[d] += rv;
        m2v[d] += rv * v2[d];
    }
}

__device__ __forceinline__ void pass0_body(
    const v2f v2[NDH], float actk,
    float& r0, v2f m1v[NDH], v2f m2v[NDH])
{
    const float rp = actk * (1.0f / 32.0f);
    r0 += rp;
    const v2f rpv = mkv2(rp, rp);
    #pragma unroll
    for (int d = 0; d < NDH; ++d) {
        const v2f rv = rpv * v2[d];
        m1v[d] += rv;
        m2v[d] += rv * v2[d];
    }
}

__device__ __forceinline__ void reduce_finalize(
    float r0, float m1[ND], float m2[ND],
    int t, int c, int wave, int lane, float inv_temp, bool last,
    float rbeta_a, float rbeta_v,
    float (&s_m1)[NRED][NC][ND], float (&s_m2)[NRED][NC][ND], float (&s_r0)[NRED][NC],
    float (&s_mu)[NC][17], float (&s_ivar)[NC][17], float (&s_A)[NC])
{
    // merge the two k-slices within each wave
    r0 += __shfl_xor(r0, 32);
    #pragma unroll
    for (int d = 0; d < ND; ++d) {
        m1[d] += __shfl_xor(m1[d], 32);
        m2[d] += __shfl_xor(m2[d], 32);
    }
    // stage 1: waves 4-7 write their group (swizzled float4 -> conflict-free)
    if (lane < 32 && wave >= NRED) {
        float4* d1 = (float4*)&s_m1[wave - NRED][c][0];
        float4* d2 = (float4*)&s_m2[wave - NRED][c][0];
        #pragma unroll
        for (int j = 0; j < 4; ++j) {
            d1[sw4(c, j)] = *(const float4*)&m1[4*j];
            d2[sw4(c, j)] = *(const float4*)&m2[4*j];
        }
        s_r0[wave - NRED][c] = r0;
    }
    __syncthreads();
    // stage 2: waves 0-3 add into their group
    if (lane < 32 && wave < NRED) {
        float4* d1 = (float4*)&s_m1[wave][c][0];
        float4* d2 = (float4*)&s_m2[wave][c][0];
        #pragma unroll
        for (int j = 0; j < 4; ++j) {
            float4 v1 = d1[sw4(c, j)];
            v1.x += m1[4*j]; v1.y += m1[4*j+1]; v1.z += m1[4*j+2]; v1.w += m1[4*j+3];
            d1[sw4(c, j)] = v1;
            float4 v2 = d2[sw4(c, j)];
            v2.x += m2[4*j]; v2.y += m2[4*j+1]; v2.z += m2[4*j+2]; v2.w += m2[4*j+3];
            d2[sw4(c, j)] = v2;
        }
        s_r0[wave][c] += r0;
    }
    __syncthreads();

    // finalize: each thread owns one (cc,d)  (NT == NC*ND == 512)
    {
        const int cc = t >> 4;
        const int d  = t & 15;
        const int fi = cc * ND + sw4(cc, d >> 2) * 4 + (d & 3);
        float am1 = 0.0f, am2 = 0.0f, ar0 = 0.0f;
        #pragma unroll
        for (int g = 0; g < NRED; ++g) {
            am1 += (&s_m1[g][0][0])[fi];
            am2 += (&s_m2[g][0][0])[fi];
            ar0 += s_r0[g][cc];
        }
        const float rs  = ar0 + EPSI;
        const float irs = __builtin_amdgcn_rcpf(rs);
        const float mu  = am1 * irs;
        // sum rp*(v-mu)^2 = m2 - 2*mu*m1 + mu^2*r0  (exact expansion)
        const float var = (am2 - mu * (2.0f * am1 - mu * ar0)) * irs + EPSI;
        const float lv  = __logf(var);
        s_mu[cc][d]   = mu;
        s_ivar[cc][d] = __builtin_amdgcn_rcpf(var);
        const float Ls = red16_sum(lv);      // sum over d (lane bits 0-3)
        if (d == 0) s_A[cc] = Ls;            // stash L; consumed below
    }
    __syncthreads();

    if (t < NC) {
        const float log2pi16 = 16.0f * 1.8378770664093453f;
        float ar0 = s_r0[0][t] + s_r0[1][t] + s_r0[2][t] + s_r0[3][t];
        const float rs = ar0 + EPSI;
        const float L  = s_A[t];
        const float costsum = rs * (16.0f * rbeta_v + 0.5f * L);
        const float x  = inv_temp * (rbeta_a - costsum);
        const float oa = 1.0f / (1.0f + __expf(-x));
        // last pass: stash oa (the output). otherwise: combined logit base
        s_A[t] = last ? oa : (__logf(oa + EPSI) - 0.5f * (log2pi16 + L));
    }
    __syncthreads();
}

__global__ __launch_bounds__(NT) void convcaps_em_kernel(
    const float* __restrict__ g_act,    // [B,196,32]
    const float* __restrict__ g_pose,   // [B,196,32,16]
    const float* __restrict__ g_W,      // [288,32,16]
    const float* __restrict__ g_beta_a, // [32]
    const float* __restrict__ g_beta_v, // [32]
    const int*   __restrict__ g_cpm,    // [144,9]
    float* __restrict__ g_out)          // act [B*144*32] then pose [B*144*32*16]
{
    __shared__ float s_pose[NK][ND];       // 18432 B
    __shared__ float s_act[NK];            // 1152 B
    __shared__ float s_m1[NRED][NC][ND];   // 8192 B
    __shared__ float s_m2[NRED][NC][ND];   // 8192 B
    __shared__ float s_r0[NRED][NC];       // 512 B
    __shared__ float s_mu[NC][17];         // 2176 B
    __shared__ float s_ivar[NC][17];       // 2176 B
    __shared__ float s_A[NC];              // 128 B   == 40960 B total

    const int bp   = blockIdx.x;
    const int b    = bp / NP;
    const int p    = bp - b * NP;
    const int t    = threadIdx.x;
    const int c    = t & 31;
    const int s    = t >> 5;
    const int wave = t >> 6;
    const int lane = t & 63;

    float rbeta_a = 0.0f, rbeta_v = 0.0f;
    if (t < NC) { rbeta_a = g_beta_a[t]; rbeta_v = g_beta_v[t]; }

    // ---- gather child poses (float4) + activations into LDS ----
    {
        const int* cpm = g_cpm + p * KW;
        const float4* pb4 = (const float4*)(g_pose + (size_t)b * (196 * CIN * ND));
        float4* sp4 = (float4*)&s_pose[0][0];
        #pragma unroll 1
        for (int i4 = t; i4 < NK * ND / 4; i4 += NT) {  // 1152 float4
            const int w   = i4 >> 7;                    // 128 float4 per window
            const int rem = i4 & 127;
            sp4[i4] = pb4[(size_t)cpm[w] * 128 + rem];
        }
        const float* ab = g_act + (size_t)b * (196 * CIN);
        if (t < NK) s_act[t] = ab[cpm[t >> 5] * CIN + (t & 31)];
    }
    __syncthreads();

    const int    k0  = s * KPT;
    const float* wp0 = g_W + (size_t)(k0 * NC + c) * ND;

    // ================= pass 0: uniform rr = 1/32 (W prefetched) =================
    {
        float r0 = 0.0f;
        v2f m1v[NDH], m2v[NDH];
        #pragma unroll
        for (int d = 0; d < NDH; ++d) { m1v[d] = mkv2(0,0); m2v[d] = mkv2(0,0); }

        v2f wrA[NDH], wrB[NDH];
        load16v(wp0, wrA);
        #pragma unroll 1
        for (int jj = 0; jj < KPT; jj += 2) {
            load16v(wp0 + (size_t)(jj + 1) * (NC * ND), wrB);
            {
                const float actk = s_act[k0 + jj];
                float pr[ND]; v2f v2[NDH];
                load16(&s_pose[k0 + jj][0], pr);
                vote44v(pr, wrA, v2);
                pass0_body(v2, actk, r0, m1v, m2v);
            }
            const int jn = (jj + 2 < KPT) ? (jj + 2) : (KPT - 1);
            load16v(wp0 + (size_t)jn * (NC * ND), wrA);
            {
                const float actk = s_act[k0 + jj + 1];
                float pr[ND]; v2f v2[NDH];
                load16(&s_pose[k0 + jj + 1][0], pr);
                vote44v(pr, wrB, v2);
                pass0_body(v2, actk, r0, m1v, m2v);
            }
        }
        float m1[ND], m2[ND];
        #pragma unroll
        for (int e = 0; e < NDH; ++e) {
            m1[2*e] = m1v[e][0]; m1[2*e+1] = m1v[e][1];
            m2[2*e] = m2v[e][0]; m2[2*e+1] = m2v[e][1];
        }
        reduce_finalize(r0, m1, m2, t, c, wave, lane, 1.0f, false, rbeta_a, rbeta_v,
                        s_m1, s_m2, s_r0, s_mu, s_ivar, s_A);
    }

    // ================= passes 1,2: E-step fused into M-step =================
    #pragma unroll 1
    for (int it = 1; it < 3; ++it) {
        // hoist per-iter stats in exp2 domain: logit2 = A2 - sum_d v*(iv2*v - 2*iv2*mu)
        const float L2E = 1.4426950408889634f;
        v2f iv2v[NDH], h2n2v[NDH];
        float gq2 = 0.0f;
        #pragma unroll
        for (int e = 0; e < NDH; ++e) {
            float ivs[2], hns[2];
            #pragma unroll
            for (int u = 0; u < 2; ++u) {
                const float mu  = s_mu[c][2*e+u];
                const float iv2 = s_ivar[c][2*e+u] * (0.5f * L2E);
                ivs[u] = iv2;
                const float h = iv2 * mu;
                hns[u] = -(h + h);
                gq2 = fmaf(h, mu, gq2);
            }
            iv2v[e]  = mkv2(ivs[0], ivs[1]);
            h2n2v[e] = mkv2(hns[0], hns[1]);
        }
        const float A2 = fmaf(L2E, s_A[c], -gq2);

        float r0 = 0.0f;
        v2f m1v[NDH], m2v[NDH];
        #pragma unroll
        for (int d = 0; d < NDH; ++d) { m1v[d] = mkv2(0,0); m2v[d] = mkv2(0,0); }

        v2f wrA[NDH], wrB[NDH];
        load16v(wp0, wrA);
        #pragma unroll 1
        for (int jj = 0; jj < KPT; jj += 2) {
            load16v(wp0 + (size_t)(jj + 1) * (NC * ND), wrB);
            {
                const float actk = s_act[k0 + jj];
                float pr[ND]; v2f v2[NDH];
                load16(&s_pose[k0 + jj][0], pr);
                vote44v(pr, wrA, v2);
                estep_body(v2, actk, iv2v, h2n2v, A2, r0, m1v, m2v);
            }
            const int jn = (jj + 2 < KPT) ? (jj + 2) : (KPT - 1);
            load16v(wp0 + (size_t)jn * (NC * ND), wrA);
            {
                const float actk = s_act[k0 + jj + 1];
                float pr[ND]; v2f v2[NDH];
                load16(&s_pose[k0 + jj + 1][0], pr);
                vote44v(pr, wrB, v2);
                estep_body(v2, actk, iv2v, h2n2v, A2, r0, m1v, m2v);
            }
        }
        float m1[ND], m2[ND];
        #pragma unroll
        for (int e = 0; e < NDH; ++e) {
            m1[2*e] = m1v[e][0]; m1[2*e+1] = m1v[e][1];
            m2[2*e] = m2v[e][0]; m2[2*e+1] = m2v[e][1];
        }
        reduce_finalize(r0, m1, m2, t, c, wave, lane, 1.0f + (float)it, it == 2,
                        rbeta_a, rbeta_v,
                        s_m1, s_m2, s_r0, s_mu, s_ivar, s_A);
    }

    // ---- write outputs: act [B,P,C] then pose [B,P,C,16] ----
    const int base = (b * NP + p) * NC;
    if (t < NC) g_out[base + t] = s_A[t];
    float* outpose = g_out + NB * NP * NC;
    {
        const int cc = t >> 4;
        const int d  = t & 15;
        outpose[(size_t)(base + cc) * ND + d] = s_mu[cc][d];
    }
}

extern "C" void kernel_launch(void* const* d_in, const int* in_sizes, int n_in,
                              void* d_out, int out_size, void* d_ws, size_t ws_size,
                              hipStream_t stream) {
    const float* in_act  = (const float*)d_in[0];
    const float* in_pose = (const float*)d_in[1];
    const float* W       = (const float*)d_in[2];
    const float* beta_a  = (const float*)d_in[3];
    const float* beta_v  = (const float*)d_in[4];
    const int*   cpm     = (const int*)d_in[5];
    float* out = (float*)d_out;

    convcaps_em_kernel<<<dim3(NB * NP), dim3(NT), 0, stream>>>(
        in_act, in_pose, W, beta_a, beta_v, cpm, out);
}

// Round 11
// 97.731 us; speedup vs baseline: 1.0350x; 1.0350x over previous
//
#include <hip/hip_runtime.h>
#include <math.h>

#define NB 4      // batch
#define NP 144    // output spatial positions (12x12)
#define KW 9      // kernel window (3x3)
#define CIN 32
#define NC 32     // output capsules
#define NK 288    // KW*CIN children
#define ND 16     // pose dims
#define NDH 8     // ND/2 (packed float2)
#define EPSI 1e-7f
#define NT 256
#define KPT 36        // k per thread
#define NRED 2        // reduction groups (waves 2-3 write, 0-1 add)

// One block per (b,p). c = t&31, s = t>>5 (k-slice 0..7), 36 k per thread.
// KEY CHANGES r11 (attack the ~400cy serial per-k chain, the identified stall):
//  (a) 2-k interleave: two independent softmax chains in flight per thread.
//  (b) half-group softmax: DPP-only max+sum within 16 lanes, then ONE parallel
//      batch of 4 ds_swizzles exchanges (m,s) across xor16; combine exactly:
//      S = s_lo*2^(m_lo-M) + s_hi*2^(m_hi-M). Serial DS waits 2x120cy -> ~120.
//  (c) NT=256: at the expected ~130-150 VGPR, 3 waves/SIMD still gives 3
//      blocks/CU (full residency); 512-thread blocks would drop to 1 block/CU.
// launch_bounds single-arg ONLY (r3/r4: 2nd arg caps VGPR at 256/arg -> spill).
// Watch: WRITE_SIZE must stay ~1.2MB; a jump = scratch spill.

typedef float v2f __attribute__((ext_vector_type(2)));

__device__ __forceinline__ v2f mkv2(float a, float b) { v2f r; r[0] = a; r[1] = b; return r; }

template<int CTRL>
__device__ __forceinline__ float dppf(float x) {
    return __int_as_float(__builtin_amdgcn_update_dpp(
        0, __float_as_int(x), CTRL, 0xF, 0xF, true));
}
// 0xB1=quad_perm xor1 ; 0x4E=quad_perm xor2 ; 0x141=row_half_mirror (xor4 once
// 4-uniform) ; 0x140=row_mirror (xor8 once 8-uniform)
__device__ __forceinline__ float swz16(float x) {
    return __int_as_float(__builtin_amdgcn_ds_swizzle(__float_as_int(x), 0x401F));
}
__device__ __forceinline__ float red16_max(float x) {
    x = fmaxf(x, dppf<0xB1>(x));
    x = fmaxf(x, dppf<0x4E>(x));
    x = fmaxf(x, dppf<0x141>(x));
    x = fmaxf(x, dppf<0x140>(x));
    return x;
}
__device__ __forceinline__ float red16_sum(float x) {
    x += dppf<0xB1>(x);
    x += dppf<0x4E>(x);
    x += dppf<0x141>(x);
    x += dppf<0x140>(x);
    return x;
}

__device__ __forceinline__ int sw4(int c, int j) { return j ^ ((c >> 1) & 3); }

__device__ __forceinline__ void load16(const float* src, float* dst) {
    const float4* s4 = (const float4*)src;
    *(float4*)&dst[0]  = s4[0];
    *(float4*)&dst[4]  = s4[1];
    *(float4*)&dst[8]  = s4[2];
    *(float4*)&dst[12] = s4[3];
}
__device__ __forceinline__ void load16v(const float* src, v2f* dst) {
    const float4* s4 = (const float4*)src;
    #pragma unroll
    for (int q = 0; q < 4; ++q) {
        const float4 tq = s4[q];
        dst[q*2+0] = mkv2(tq.x, tq.y);
        dst[q*2+1] = mkv2(tq.z, tq.w);
    }
}

// vote pairs: v2[i*2+p] = {vote[i*4+2p], vote[i*4+2p+1]}
__device__ __forceinline__ void vote44v(const float* pr, const v2f* wr2, v2f* v2) {
    #pragma unroll
    for (int i = 0; i < 4; ++i) {
        const v2f p0 = mkv2(pr[i*4+0], pr[i*4+0]);
        const v2f p1 = mkv2(pr[i*4+1], pr[i*4+1]);
        const v2f p2 = mkv2(pr[i*4+2], pr[i*4+2]);
        const v2f p3 = mkv2(pr[i*4+3], pr[i*4+3]);
        #pragma unroll
        for (int p = 0; p < 2; ++p) {
            v2f acc = p0 * wr2[0*2+p];
            acc += p1 * wr2[1*2+p];
            acc += p2 * wr2[2*2+p];
            acc += p3 * wr2[3*2+p];
            v2[i*2+p] = acc;
        }
    }
}

__device__ __forceinline__ void reduce_finalize(
    float r0, v2f m1v[NDH], v2f m2v[NDH],
    int t, int c, int wave, int lane, float inv_temp, bool last,
    float rbeta_a, float rbeta_v,
    float (&s_m1)[NRED][NC][ND], float (&s_m2)[NRED][NC][ND], float (&s_r0)[NRED][NC],
    float (&s_mu)[NC][17], float (&s_ivar)[NC][17], float (&s_A)[NC])
{
    float m1[ND], m2[ND];
    #pragma unroll
    for (int e = 0; e < NDH; ++e) {
        m1[2*e] = m1v[e][0]; m1[2*e+1] = m1v[e][1];
        m2[2*e] = m2v[e][0]; m2[2*e+1] = m2v[e][1];
    }
    // merge the two k-slices within each wave
    r0 += __shfl_xor(r0, 32);
    #pragma unroll
    for (int d = 0; d < ND; ++d) {
        m1[d] += __shfl_xor(m1[d], 32);
        m2[d] += __shfl_xor(m2[d], 32);
    }
    // stage 1: waves 2,3 write groups 0,1 (swizzled float4 -> conflict-free)
    if (lane < 32 && wave >= NRED) {
        float4* d1 = (float4*)&s_m1[wave - NRED][c][0];
        float4* d2 = (float4*)&s_m2[wave - NRED][c][0];
        #pragma unroll
        for (int j = 0; j < 4; ++j) {
            d1[sw4(c, j)] = *(const float4*)&m1[4*j];
            d2[sw4(c, j)] = *(const float4*)&m2[4*j];
        }
        s_r0[wave - NRED][c] = r0;
    }
    __syncthreads();
    // stage 2: waves 0,1 add into their group
    if (lane < 32 && wave < NRED) {
        float4* d1 = (float4*)&s_m1[wave][c][0];
        float4* d2 = (float4*)&s_m2[wave][c][0];
        #pragma unroll
        for (int j = 0; j < 4; ++j) {
            float4 v1 = d1[sw4(c, j)];
            v1.x += m1[4*j]; v1.y += m1[4*j+1]; v1.z += m1[4*j+2]; v1.w += m1[4*j+3];
            d1[sw4(c, j)] = v1;
            float4 v2 = d2[sw4(c, j)];
            v2.x += m2[4*j]; v2.y += m2[4*j+1]; v2.z += m2[4*j+2]; v2.w += m2[4*j+3];
            d2[sw4(c, j)] = v2;
        }
        s_r0[wave][c] += r0;
    }
    __syncthreads();

    // finalize: 512 (cc,d) items over 256 threads -> 2 per thread
    #pragma unroll
    for (int m = 0; m < 2; ++m) {
        const int item = t + m * NT;
        const int cc = item >> 4;
        const int d  = item & 15;
        const int fi = cc * ND + sw4(cc, d >> 2) * 4 + (d & 3);
        const float am1 = (&s_m1[0][0][0])[fi] + (&s_m1[1][0][0])[fi];
        const float am2 = (&s_m2[0][0][0])[fi] + (&s_m2[1][0][0])[fi];
        const float ar0 = s_r0[0][cc] + s_r0[1][cc];
        const float rs  = ar0 + EPSI;
        const float irs = __builtin_amdgcn_rcpf(rs);
        const float mu  = am1 * irs;
        // sum rp*(v-mu)^2 = m2 - 2*mu*m1 + mu^2*r0  (exact expansion)
        const float var = (am2 - mu * (2.0f * am1 - mu * ar0)) * irs + EPSI;
        const float lv  = __logf(var);
        s_mu[cc][d]   = mu;
        s_ivar[cc][d] = __builtin_amdgcn_rcpf(var);
        const float Ls = red16_sum(lv);      // sum over d (lane bits 0-3)
        if (d == 0) s_A[cc] = Ls;            // stash L; consumed below
    }
    __syncthreads();

    if (t < NC) {
        const float log2pi16 = 16.0f * 1.8378770664093453f;
        const float ar0 = s_r0[0][t] + s_r0[1][t];
        const float rs = ar0 + EPSI;
        const float L  = s_A[t];
        const float costsum = rs * (16.0f * rbeta_v + 0.5f * L);
        const float x  = inv_temp * (rbeta_a - costsum);
        const float oa = 1.0f / (1.0f + __expf(-x));
        // last pass: stash oa (the output). otherwise: combined logit base
        s_A[t] = last ? oa : (__logf(oa + EPSI) - 0.5f * (log2pi16 + L));
    }
    __syncthreads();
}

__global__ __launch_bounds__(NT) void convcaps_em_kernel(
    const float* __restrict__ g_act,    // [B,196,32]
    const float* __restrict__ g_pose,   // [B,196,32,16]
    const float* __restrict__ g_W,      // [288,32,16]
    const float* __restrict__ g_beta_a, // [32]
    const float* __restrict__ g_beta_v, // [32]
    const int*   __restrict__ g_cpm,    // [144,9]
    float* __restrict__ g_out)          // act [B*144*32] then pose [B*144*32*16]
{
    __shared__ float s_pose[NK][ND];       // 18432 B
    __shared__ float s_act[NK];            // 1152 B
    __shared__ float s_m1[NRED][NC][ND];   // 4096 B
    __shared__ float s_m2[NRED][NC][ND];   // 4096 B
    __shared__ float s_r0[NRED][NC];       // 256 B
    __shared__ float s_mu[NC][17];         // 2176 B
    __shared__ float s_ivar[NC][17];       // 2176 B
    __shared__ float s_A[NC];              // 128 B   ~= 32.5 KB -> 4 blk/CU LDS-wise

    const int bp   = blockIdx.x;
    const int b    = bp / NP;
    const int p    = bp - b * NP;
    const int t    = threadIdx.x;
    const int c    = t & 31;
    const int s    = t >> 5;
    const int wave = t >> 6;
    const int lane = t & 63;

    float rbeta_a = 0.0f, rbeta_v = 0.0f;
    if (t < NC) { rbeta_a = g_beta_a[t]; rbeta_v = g_beta_v[t]; }

    // ---- gather child poses (float4) + activations into LDS ----
    {
        const int* cpm = g_cpm + p * KW;
        const float4* pb4 = (const float4*)(g_pose + (size_t)b * (196 * CIN * ND));
        float4* sp4 = (float4*)&s_pose[0][0];
        #pragma unroll 1
        for (int i4 = t; i4 < NK * ND / 4; i4 += NT) {  // 1152 float4
            const int w   = i4 >> 7;                    // 128 float4 per window
            const int rem = i4 & 127;
            sp4[i4] = pb4[(size_t)cpm[w] * 128 + rem];
        }
        #pragma unroll 1
        for (int e = t; e < NK; e += NT)
            s_act[e] = g_act[(size_t)b * (196 * CIN) + cpm[e >> 5] * CIN + (e & 31)];
    }
    __syncthreads();

    const int    k0  = s * KPT;
    const float* wp0 = g_W + (size_t)(k0 * NC + c) * ND;

    // ================= pass 0: uniform rr = 1/32, 2-k bodies =================
    {
        float r0 = 0.0f;
        v2f m1v[NDH], m2v[NDH];
        #pragma unroll
        for (int d = 0; d < NDH; ++d) { m1v[d] = mkv2(0,0); m2v[d] = mkv2(0,0); }

        const float* wp = wp0;
        #pragma unroll 1
        for (int jj = 0; jj < KPT; jj += 2, wp += 2 * NC * ND) {
            float pr[ND]; v2f wr[NDH];
            v2f va[NDH], vb[NDH];
            load16(&s_pose[k0 + jj][0], pr);
            load16v(wp, wr);
            vote44v(pr, wr, va);
            load16(&s_pose[k0 + jj + 1][0], pr);
            load16v(wp + NC * ND, wr);
            vote44v(pr, wr, vb);

            const float2 a2 = *(const float2*)&s_act[k0 + jj];
            const float rpa = a2.x * (1.0f / 32.0f);
            const float rpb = a2.y * (1.0f / 32.0f);
            r0 += rpa + rpb;
            const v2f rpav = mkv2(rpa, rpa), rpbv = mkv2(rpb, rpb);
            #pragma unroll
            for (int d = 0; d < NDH; ++d) {
                const v2f rva = rpav * va[d];
                const v2f rvb = rpbv * vb[d];
                m1v[d] += rva + rvb;
                m2v[d] += rva * va[d] + rvb * vb[d];
            }
        }
        reduce_finalize(r0, m1v, m2v, t, c, wave, lane, 1.0f, false, rbeta_a, rbeta_v,
                        s_m1, s_m2, s_r0, s_mu, s_ivar, s_A);
    }

    // ================= passes 1,2: E-step fused, 2-k interleaved =================
    #pragma unroll 1
    for (int it = 1; it < 3; ++it) {
        // hoist per-iter stats in exp2 domain
        const float L2E = 1.4426950408889634f;
        v2f iv2v[NDH], h2n2v[NDH];
        float gq2 = 0.0f;
        #pragma unroll
        for (int e = 0; e < NDH; ++e) {
            float ivs[2], hns[2];
            #pragma unroll
            for (int u = 0; u < 2; ++u) {
                const float mu  = s_mu[c][2*e+u];
                const float iv2 = s_ivar[c][2*e+u] * (0.5f * L2E);
                ivs[u] = iv2;
                const float h = iv2 * mu;
                hns[u] = -(h + h);
                gq2 = fmaf(h, mu, gq2);
            }
            iv2v[e]  = mkv2(ivs[0], ivs[1]);
            h2n2v[e] = mkv2(hns[0], hns[1]);
        }
        const float A2 = fmaf(L2E, s_A[c], -gq2);

        float r0 = 0.0f;
        v2f m1v[NDH], m2v[NDH];
        #pragma unroll
        for (int d = 0; d < NDH; ++d) { m1v[d] = mkv2(0,0); m2v[d] = mkv2(0,0); }

        const float* wp = wp0;
        #pragma unroll 1
        for (int jj = 0; jj < KPT; jj += 2, wp += 2 * NC * ND) {
            float pr[ND]; v2f wr[NDH];
            v2f va[NDH], vb[NDH];
            load16(&s_pose[k0 + jj][0], pr);
            load16v(wp, wr);
            vote44v(pr, wr, va);
            load16(&s_pose[k0 + jj + 1][0], pr);
            load16v(wp + NC * ND, wr);
            vote44v(pr, wr, vb);

            // logits (two independent chains)
            v2f qa2 = mkv2(0,0), qb2 = mkv2(0,0);
            #pragma unroll
            for (int e = 0; e < NDH; ++e) {
                qa2 += (iv2v[e] * va[e] + h2n2v[e]) * va[e];
                qb2 += (iv2v[e] * vb[e] + h2n2v[e]) * vb[e];
            }
            const float la = A2 - (qa2[0] + qa2[1]);
            const float lb = A2 - (qb2[0] + qb2[1]);

            // 16-group max + sum (DPP only), interleaved a/b
            const float ma = red16_max(la);
            const float mb = red16_max(lb);
            const float ea = __builtin_amdgcn_exp2f(la - ma);
            const float eb = __builtin_amdgcn_exp2f(lb - mb);
            const float sa = red16_sum(ea);
            const float sb = red16_sum(eb);
            // exchange (m,s) across xor16: 4 independent swizzles, one wait
            const float mao = swz16(ma);
            const float sao = swz16(sa);
            const float mbo = swz16(mb);
            const float sbo = swz16(sb);
            const float Ma = fmaxf(ma, mao);
            const float Mb = fmaxf(mb, mbo);
            const float wa = __builtin_amdgcn_exp2f(ma - Ma);
            const float wb = __builtin_amdgcn_exp2f(mb - Mb);
            const float Sa = fmaf(sao, __builtin_amdgcn_exp2f(mao - Ma), sa * wa);
            const float Sb = fmaf(sbo, __builtin_amdgcn_exp2f(mbo - Mb), sb * wb);

            const float2 a2 = *(const float2*)&s_act[k0 + jj];
            const float rpa = ea * wa * __builtin_amdgcn_rcpf(Sa) * a2.x;
            const float rpb = eb * wb * __builtin_amdgcn_rcpf(Sb) * a2.y;
            r0 += rpa + rpb;
            const v2f rpav = mkv2(rpa, rpa), rpbv = mkv2(rpb, rpb);
            #pragma unroll
            for (int d = 0; d < NDH; ++d) {
                const v2f rva = rpav * va[d];
                const v2f rvb = rpbv * vb[d];
                m1v[d] += rva + rvb;
                m2v[d] += rva * va[d] + rvb * vb[d];
            }
        }
        reduce_finalize(r0, m1v, m2v, t, c, wave, lane, 1.0f + (float)it, it == 2,
                        rbeta_a, rbeta_v,
                        s_m1, s_m2, s_r0, s_mu, s_ivar, s_A);
    }

    // ---- write outputs: act [B,P,C] then pose [B,P,C,16] ----
    const int base = (b * NP + p) * NC;
    if (t < NC) g_out[base + t] = s_A[t];
    float* outpose = g_out + NB * NP * NC;
    #pragma unroll
    for (int m = 0; m < 2; ++m) {
        const int item = t + m * NT;
        const int cc = item >> 4;
        const int d  = item & 15;
        outpose[(size_t)(base + cc) * ND + d] = s_mu[cc][d];
    }
}

extern "C" void kernel_launch(void* const* d_in, const int* in_sizes, int n_in,
                              void* d_out, int out_size, void* d_ws, size_t ws_size,
                              hipStream_t stream) {
    const float* in_act  = (const float*)d_in[0];
    const float* in_pose = (const float*)d_in[1];
    const float* W       = (const float*)d_in[2];
    const float* beta_a  = (const float*)d_in[3];
    const float* beta_v  = (const float*)d_in[4];
    const int*   cpm     = (const int*)d_in[5];
    float* out = (float*)d_out;

    convcaps_em_kernel<<<dim3(NB * NP), dim3(NT), 0, stream>>>(
        in_act, in_pose, W, beta_a, beta_v, cpm, out);
}